// Round 8
// baseline (1248.300 us; speedup 1.0000x reference)
//
#include <hip/hip_runtime.h>

#define E_CNT 500000
#define N_CNT 50000
#define DD 128
#define HH 256
#define LN_EPS 1e-5f

typedef __attribute__((ext_vector_type(8))) short bh8;   // 8 x bf16 (MFMA A/B frag)
typedef __attribute__((ext_vector_type(4))) float fx4;   // MFMA C/D frag

__device__ __forceinline__ float b2f(short s) {
    return __uint_as_float(((unsigned)(unsigned short)s) << 16);
}
__device__ __forceinline__ short f2b(float f) {
    unsigned x = __float_as_uint(f);
    x += 0x7fffu + ((x >> 16) & 1u);   // RNE
    return (short)(x >> 16);
}
__device__ __forceinline__ fx4 mfma16(bh8 a, bh8 b, fx4 c) {
    return __builtin_amdgcn_mfma_f32_16x16x32_bf16(a, b, c, 0, 0, 0);
}
// byte-offset XOR swizzle for a [*][128] bf16 plane (256B rows)
__device__ __forceinline__ int swz128(int row, int k) {
    return ((row * 128 + k) * 2) ^ ((row & 7) << 4);
}
__device__ __forceinline__ int swz256(int row, int c) {   // [*][256] bf16 tile
    return ((row * 256 + c) * 2) ^ ((row & 7) << 4);
}
__device__ __forceinline__ bh8 pack8(const float* s) {
    float4 f0 = *(const float4*)s, f1 = *(const float4*)(s + 4);
    bh8 v;
    v[0] = f2b(f0.x); v[1] = f2b(f0.y); v[2] = f2b(f0.z); v[3] = f2b(f0.w);
    v[4] = f2b(f1.x); v[5] = f2b(f1.y); v[6] = f2b(f1.z); v[7] = f2b(f1.w);
    return v;
}
// async global->LDS, 16B/lane; dest = uniform base + lane*16 (HW rule)
__device__ __forceinline__ void dma16(const void* g, void* l) {
    __builtin_amdgcn_global_load_lds(
        (const __attribute__((address_space(1))) void*)g,
        (__attribute__((address_space(3))) void*)l, 16, 0, 0);
}

// ---------------------------------------------------------------------------
__global__ void wtrans(const float* __restrict__ src, short* __restrict__ dst,
                       int K, int N) {
    int idx = blockIdx.x * 256 + threadIdx.x;
    if (idx >= K * N) return;
    int n = idx / K, k = idx - n * K;
    dst[idx] = f2b(src[(size_t)k * N + n]);
}

__global__ void castbf(const float* __restrict__ src, short* __restrict__ dst, int n8) {
    int i = blockIdx.x * 256 + threadIdx.x;
    if (i < n8) *(bh8*)(dst + (size_t)i * 8) = pack8(src + (size_t)i * 8);
}

// ---------------------------------------------------------------------------
// Edge kernel v7 (UNCHANGED from R7 -> comparable FULL reference)
// ---------------------------------------------------------------------------
__launch_bounds__(512, 2)
__global__ void edge_kernel(const float* __restrict__ edges,
                            const int* __restrict__ senders,
                            const int* __restrict__ receivers,
                            const short* __restrict__ nodesBF, // [N][128] bf16
                            const short* __restrict__ eW1t,    // [256][384]
                            const short* __restrict__ eW2t,    // [128][256]
                            const float* __restrict__ eb1,
                            const float* __restrict__ eg,
                            const float* __restrict__ ebt,
                            const float* __restrict__ eb2,
                            float* __restrict__ agg,
                            float* __restrict__ edges_out) {
    __shared__ short Apl[3][64 * 128];   // 48KB: edges | senders | receivers
    __shared__ float P[64][4][2];        // LN partials [row][wn][sum,sumsq]

    const int tid = threadIdx.x;
    const int l = tid & 63, wid = tid >> 6, lg = l >> 4, lo = l & 15;
    const int e0 = blockIdx.x * 64;

    float4 ef[2][2];
    #pragma unroll
    for (int it = 0; it < 2; ++it) {
        int ch = tid + 512 * it;
        int row = ch >> 4, c = ch & 15;
        int e = e0 + row; if (e >= E_CNT) e = E_CNT - 1;
        const float* p = edges + (size_t)e * DD + c * 8;
        ef[it][0] = *(const float4*)p;
        ef[it][1] = *(const float4*)(p + 4);
    }
    int dmaIdx[4], dmaRow[4];
    #pragma unroll
    for (int q = 0; q < 4; ++q) {
        int qq = wid * 4 + q;
        int r = (qq & 15) * 4 + lg;
        int e = e0 + r; if (e >= E_CNT) e = E_CNT - 1;
        dmaIdx[q] = (qq < 16 ? senders : receivers)[e];
        dmaRow[q] = r;
    }
    #pragma unroll
    for (int it = 0; it < 2; ++it) {
        int ch = tid + 512 * it;
        int row = ch >> 4, c = ch & 15;
        bh8 v;
        v[0] = f2b(ef[it][0].x); v[1] = f2b(ef[it][0].y);
        v[2] = f2b(ef[it][0].z); v[3] = f2b(ef[it][0].w);
        v[4] = f2b(ef[it][1].x); v[5] = f2b(ef[it][1].y);
        v[6] = f2b(ef[it][1].z); v[7] = f2b(ef[it][1].w);
        *(bh8*)((char*)Apl[0] + swz128(row, c * 8)) = v;
    }
    #pragma unroll
    for (int q = 0; q < 4; ++q) {
        int qq = wid * 4 + q;
        int r = dmaRow[q];
        const short* src = nodesBF + (size_t)dmaIdx[q] * DD + ((lo ^ (r & 7)) * 8);
        short* dst = Apl[qq < 16 ? 1 : 2] + (qq & 15) * 4 * 128;
        dma16(src, dst);
    }
    __builtin_amdgcn_sched_barrier(0);
    asm volatile("s_waitcnt lgkmcnt(0)" ::: "memory");
    __builtin_amdgcn_s_barrier();
    __builtin_amdgcn_sched_barrier(0);

    const int wn = wid & 3, wm = wid >> 2;
    const int wn2 = wid & 1, wm2 = wid >> 1;
    float eb1c[4], egc[4], ebtc[4], eb2c[4];
    #pragma unroll
    for (int j = 0; j < 4; ++j) {
        int col = wn * 64 + 16 * j + lo;
        eb1c[j] = eb1[col]; egc[j] = eg[col]; ebtc[j] = ebt[col];
        eb2c[j] = eb2[wn2 * 64 + 16 * j + lo];
    }

    fx4 acc[2][4] = {};
    #pragma unroll
    for (int kk = 0; kk < 4; ++kk) {
        int krow = kk * 32 + lg * 8;
        bh8 a[2], b[4];
        #pragma unroll
        for (int i = 0; i < 2; ++i)
            a[i] = *(const bh8*)((char*)Apl[0] + swz128(wm * 32 + 16 * i + lo, krow));
        #pragma unroll
        for (int j = 0; j < 4; ++j)
            b[j] = *(const bh8*)(eW1t + (size_t)(wn * 64 + 16 * j + lo) * 384 + krow);
        #pragma unroll
        for (int i = 0; i < 2; ++i)
            #pragma unroll
            for (int j = 0; j < 4; ++j)
                acc[i][j] = mfma16(a[i], b[j], acc[i][j]);
    }
    asm volatile("s_waitcnt vmcnt(0)" ::: "memory");
    __builtin_amdgcn_s_barrier();
    __builtin_amdgcn_sched_barrier(0);

    #pragma unroll
    for (int kk = 4; kk < 12; ++kk) {
        int p = kk >> 2;
        int krow = (kk & 3) * 32 + lg * 8;
        bh8 a[2], b[4];
        #pragma unroll
        for (int i = 0; i < 2; ++i)
            a[i] = *(const bh8*)((char*)Apl[p] + swz128(wm * 32 + 16 * i + lo, krow));
        #pragma unroll
        for (int j = 0; j < 4; ++j)
            b[j] = *(const bh8*)(eW1t + (size_t)(wn * 64 + 16 * j + lo) * 384 + p * 128 + krow);
        #pragma unroll
        for (int i = 0; i < 2; ++i)
            #pragma unroll
            for (int j = 0; j < 4; ++j)
                acc[i][j] = mfma16(a[i], b[j], acc[i][j]);
    }

    #pragma unroll
    for (int i = 0; i < 2; ++i)
        #pragma unroll
        for (int r = 0; r < 4; ++r) {
            int row = wm * 32 + 16 * i + lg * 4 + r;
            float s = 0.f, q = 0.f;
            #pragma unroll
            for (int j = 0; j < 4; ++j) {
                float v = acc[i][j][r] + eb1c[j];
                acc[i][j][r] = v;
                s += v; q += v * v;
            }
            #pragma unroll
            for (int m = 1; m < 16; m <<= 1) {
                s += __shfl_xor(s, m);
                q += __shfl_xor(q, m);
            }
            if (lo == 0) { P[row][wn][0] = s; P[row][wn][1] = q; }
        }
    asm volatile("s_waitcnt lgkmcnt(0)" ::: "memory");
    __builtin_amdgcn_s_barrier();
    __builtin_amdgcn_sched_barrier(0);

    #pragma unroll
    for (int i = 0; i < 2; ++i)
        #pragma unroll
        for (int r = 0; r < 4; ++r) {
            int row = wm * 32 + 16 * i + lg * 4 + r;
            float s = P[row][0][0] + P[row][1][0] + P[row][2][0] + P[row][3][0];
            float q = P[row][0][1] + P[row][1][1] + P[row][2][1] + P[row][3][1];
            float mean = s * (1.0f / 256.0f);
            float var = q * (1.0f / 256.0f) - mean * mean;
            float rstd = rsqrtf(var + LN_EPS);
            #pragma unroll
            for (int j = 0; j < 4; ++j) {
                int col = wn * 64 + 16 * j + lo;
                float v = (acc[i][j][r] - mean) * rstd * egc[j] + ebtc[j];
                v = fmaxf(v, 0.0f);
                *(short*)((char*)Apl[1 + (col >> 7)] + swz128(row, col & 127)) = f2b(v);
            }
        }
    asm volatile("s_waitcnt lgkmcnt(0)" ::: "memory");
    __builtin_amdgcn_s_barrier();
    __builtin_amdgcn_sched_barrier(0);

    fx4 acc2[4] = {};
    #pragma unroll
    for (int kk = 0; kk < 8; ++kk) {
        int k0 = kk * 32 + lg * 8;
        bh8 a2 = *(const bh8*)((char*)Apl[1 + (k0 >> 7)] + swz128(wm2 * 16 + lo, k0 & 127));
        #pragma unroll
        for (int j = 0; j < 4; ++j) {
            bh8 b = *(const bh8*)(eW2t + (size_t)(wn2 * 64 + 16 * j + lo) * HH + k0);
            acc2[j] = mfma16(a2, b, acc2[j]);
        }
    }
    int eR[4], rcv[4];
    #pragma unroll
    for (int r = 0; r < 4; ++r) {
        int e = e0 + wm2 * 16 + lg * 4 + r;
        eR[r] = e;
        rcv[r] = receivers[e < E_CNT ? e : E_CNT - 1];
    }
    #pragma unroll
    for (int j = 0; j < 4; ++j) {
        #pragma unroll
        for (int r = 0; r < 4; ++r) {
            if (eR[r] < E_CNT) {
                int row = wm2 * 16 + lg * 4 + r;
                int col = wn2 * 64 + 16 * j + lo;
                float upd = acc2[j][r] + eb2c[j];
                float res = b2f(*(const short*)((char*)Apl[0] + swz128(row, col)));
                edges_out[(size_t)eR[r] * DD + col] = upd + res;
                atomicAdd(agg + (size_t)rcv[r] * DD + col, upd);
            }
        }
    }
}

// ---------------------------------------------------------------------------
// ABLATION 1: stage-only, x4 cold tiles per block -> dur/4 = un-overlapped
// stage cost (edge HBM loads + f2b + LDS write + DMA gathers + drain).
// ---------------------------------------------------------------------------
__launch_bounds__(512, 2)
__global__ void abl_stage4(const float* __restrict__ edges,
                           const int* __restrict__ senders,
                           const int* __restrict__ receivers,
                           const short* __restrict__ nodesBF,
                           float* __restrict__ sinkbuf) {
    __shared__ short Apl[3][64 * 128];
    const int tid = threadIdx.x;
    const int l = tid & 63, wid = tid >> 6, lg = l >> 4, lo = l & 15;
    int accv = 0;

    for (int t = 0; t < 4; ++t) {
        const int e0 = (blockIdx.x * 4 + t) * 64;

        float4 ef[2][2];
        #pragma unroll
        for (int it = 0; it < 2; ++it) {
            int ch = tid + 512 * it;
            int row = ch >> 4, c = ch & 15;
            int e = e0 + row; if (e >= E_CNT) e = E_CNT - 1;
            const float* p = edges + (size_t)e * DD + c * 8;
            ef[it][0] = *(const float4*)p;
            ef[it][1] = *(const float4*)(p + 4);
        }
        int dmaIdx[4], dmaRow[4];
        #pragma unroll
        for (int q = 0; q < 4; ++q) {
            int qq = wid * 4 + q;
            int r = (qq & 15) * 4 + lg;
            int e = e0 + r; if (e >= E_CNT) e = E_CNT - 1;
            dmaIdx[q] = (qq < 16 ? senders : receivers)[e];
            dmaRow[q] = r;
        }
        #pragma unroll
        for (int it = 0; it < 2; ++it) {
            int ch = tid + 512 * it;
            int row = ch >> 4, c = ch & 15;
            bh8 v;
            v[0] = f2b(ef[it][0].x); v[1] = f2b(ef[it][0].y);
            v[2] = f2b(ef[it][0].z); v[3] = f2b(ef[it][0].w);
            v[4] = f2b(ef[it][1].x); v[5] = f2b(ef[it][1].y);
            v[6] = f2b(ef[it][1].z); v[7] = f2b(ef[it][1].w);
            *(bh8*)((char*)Apl[0] + swz128(row, c * 8)) = v;
        }
        #pragma unroll
        for (int q = 0; q < 4; ++q) {
            int qq = wid * 4 + q;
            int r = dmaRow[q];
            const short* src = nodesBF + (size_t)dmaIdx[q] * DD + ((lo ^ (r & 7)) * 8);
            short* dst = Apl[qq < 16 ? 1 : 2] + (qq & 15) * 4 * 128;
            dma16(src, dst);
        }
        __builtin_amdgcn_sched_barrier(0);
        asm volatile("s_waitcnt vmcnt(0) lgkmcnt(0)" ::: "memory");
        __builtin_amdgcn_s_barrier();
        __builtin_amdgcn_sched_barrier(0);
        // keep everything live (rule #17): consume all three planes
        accv ^= ((const int*)Apl[0])[tid] ^ ((const int*)Apl[1])[tid]
              ^ ((const int*)Apl[2])[tid];
        __builtin_amdgcn_s_barrier();   // safe overwrite next iter
    }
    sinkbuf[(size_t)blockIdx.x * 512 + tid] = (float)accv;
}

// ---------------------------------------------------------------------------
// ABLATION 2: pure atomic replay, x2 passes (disjoint addr sets) -> dur/2 =
// device fp32-atomicAdd floor for the real 64M-op epilogue pattern.
// ---------------------------------------------------------------------------
__launch_bounds__(512, 2)
__global__ void abl_atomic2(const int* __restrict__ receivers,
                            float* __restrict__ aggscr) {
    const int tid = threadIdx.x;
    const int l = tid & 63, wid = tid >> 6, lg = l >> 4, lo = l & 15;
    const int wm2 = wid >> 1, wn2 = wid & 1;
    const int e0 = blockIdx.x * 64;
    int rcv[4];
    #pragma unroll
    for (int r = 0; r < 4; ++r) {
        int e = e0 + wm2 * 16 + lg * 4 + r;
        rcv[r] = receivers[e < E_CNT ? e : E_CNT - 1];
    }
    #pragma unroll
    for (int pass = 0; pass < 2; ++pass) {
        #pragma unroll
        for (int j = 0; j < 4; ++j) {
            #pragma unroll
            for (int r = 0; r < 4; ++r) {
                int col = wn2 * 64 + 16 * j + lo;
                int node = rcv[r] + pass * 12345;
                if (node >= N_CNT) node -= N_CNT;
                atomicAdd(aggscr + (size_t)node * DD + col, 1.0f);
            }
        }
    }
}

// ---------------------------------------------------------------------------
// Node kernel (unchanged)
// ---------------------------------------------------------------------------
__launch_bounds__(512, 2)
__global__ void node_kernel(const float* __restrict__ nodes,
                            const float* __restrict__ agg,
                            const short* __restrict__ nW1t,   // [256][256]
                            const short* __restrict__ nW2t,   // [128][256]
                            const float* __restrict__ nb1,
                            const float* __restrict__ ng,
                            const float* __restrict__ nbt,
                            const float* __restrict__ nb2,
                            float* __restrict__ nodes_out) {
    __shared__ char X[64 * 256 * 2];
    __shared__ float P[64][4][2];

    const int tid = threadIdx.x;
    const int l = tid & 63, wid = tid >> 6;
    const int n0 = blockIdx.x * 64;

    #pragma unroll
    for (int it = 0; it < 4; ++it) {
        int c = tid + 512 * it;
        int row = c >> 5, cc = (c & 31) * 8;
        int n = n0 + row; if (n >= N_CNT) n = N_CNT - 1;
        const float* s = (cc < DD) ? (nodes + (size_t)n * DD + cc)
                                   : (agg + (size_t)n * DD + (cc - DD));
        *(bh8*)(X + swz256(row, cc)) = pack8(s);
    }
    __syncthreads();

    const int wm = wid >> 2, wn = wid & 3;
    fx4 acc[2][4] = {};
    #pragma unroll
    for (int kk = 0; kk < 8; ++kk) {
        int krow = kk * 32 + (l >> 4) * 8;
        bh8 a[2], b[4];
        #pragma unroll
        for (int i = 0; i < 2; ++i)
            a[i] = *(const bh8*)(X + swz256(wm * 32 + 16 * i + (l & 15), krow));
        #pragma unroll
        for (int j = 0; j < 4; ++j)
            b[j] = *(const bh8*)(nW1t + (size_t)(wn * 64 + 16 * j + (l & 15)) * 256 + krow);
        #pragma unroll
        for (int i = 0; i < 2; ++i)
            #pragma unroll
            for (int j = 0; j < 4; ++j)
                acc[i][j] = mfma16(a[i], b[j], acc[i][j]);
    }
    __syncthreads();

    float nb1c[4], ngc[4], nbtc[4];
    #pragma unroll
    for (int j = 0; j < 4; ++j) {
        int col = wn * 64 + 16 * j + (l & 15);
        nb1c[j] = nb1[col]; ngc[j] = ng[col]; nbtc[j] = nbt[col];
    }
    #pragma unroll
    for (int i = 0; i < 2; ++i)
        #pragma unroll
        for (int r = 0; r < 4; ++r) {
            int row = wm * 32 + 16 * i + (l >> 4) * 4 + r;
            float s = 0.f, q = 0.f;
            #pragma unroll
            for (int j = 0; j < 4; ++j) {
                float v = acc[i][j][r] + nb1c[j];
                acc[i][j][r] = v;
                s += v; q += v * v;
            }
            #pragma unroll
            for (int m = 1; m < 16; m <<= 1) {
                s += __shfl_xor(s, m);
                q += __shfl_xor(q, m);
            }
            if ((l & 15) == 0) { P[row][wn][0] = s; P[row][wn][1] = q; }
        }
    __syncthreads();

    #pragma unroll
    for (int i = 0; i < 2; ++i)
        #pragma unroll
        for (int r = 0; r < 4; ++r) {
            int row = wm * 32 + 16 * i + (l >> 4) * 4 + r;
            float s = P[row][0][0] + P[row][1][0] + P[row][2][0] + P[row][3][0];
            float q = P[row][0][1] + P[row][1][1] + P[row][2][1] + P[row][3][1];
            float mean = s * (1.0f / 256.0f);
            float var = q * (1.0f / 256.0f) - mean * mean;
            float rstd = rsqrtf(var + LN_EPS);
            #pragma unroll
            for (int j = 0; j < 4; ++j) {
                int col = wn * 64 + 16 * j + (l & 15);
                float v = (acc[i][j][r] - mean) * rstd * ngc[j] + nbtc[j];
                v = fmaxf(v, 0.0f);
                *(short*)(X + swz256(row, col)) = f2b(v);
            }
        }
    __syncthreads();

    const int wm2 = wid >> 1, wn2 = wid & 1;
    fx4 acc2[4] = {};
    #pragma unroll
    for (int kk = 0; kk < 8; ++kk) {
        int krow = kk * 32 + (l >> 4) * 8;
        bh8 a = *(const bh8*)(X + swz256(wm2 * 16 + (l & 15), krow));
        #pragma unroll
        for (int j = 0; j < 4; ++j) {
            bh8 b = *(const bh8*)(nW2t + (size_t)(wn2 * 64 + 16 * j + (l & 15)) * 256 + krow);
            acc2[j] = mfma16(a, b, acc2[j]);
        }
    }
    float nb2c[4];
    #pragma unroll
    for (int j = 0; j < 4; ++j) nb2c[j] = nb2[wn2 * 64 + 16 * j + (l & 15)];
    #pragma unroll
    for (int r = 0; r < 4; ++r) {
        int row = wm2 * 16 + (l >> 4) * 4 + r;
        int n = n0 + row;
        if (n < N_CNT) {
            #pragma unroll
            for (int j = 0; j < 4; ++j) {
                int col = wn2 * 64 + 16 * j + (l & 15);
                nodes_out[(size_t)n * DD + col] =
                    acc2[j][r] + nb2c[j] + nodes[(size_t)n * DD + col];
            }
        }
    }
}

// ---------------------------------------------------------------------------
extern "C" void kernel_launch(void* const* d_in, const int* in_sizes, int n_in,
                              void* d_out, int out_size, void* d_ws, size_t ws_size,
                              hipStream_t stream) {
    const float* nodes = (const float*)d_in[0];
    const float* edges = (const float*)d_in[1];
    const int* senders = (const int*)d_in[2];
    const int* receivers = (const int*)d_in[3];
    const float* eW1 = (const float*)d_in[4];
    const float* eb1 = (const float*)d_in[5];
    const float* eg  = (const float*)d_in[6];
    const float* ebt = (const float*)d_in[7];
    const float* eW2 = (const float*)d_in[8];
    const float* eb2 = (const float*)d_in[9];
    const float* nW1 = (const float*)d_in[10];
    const float* nb1 = (const float*)d_in[11];
    const float* ng  = (const float*)d_in[12];
    const float* nbt = (const float*)d_in[13];
    const float* nW2 = (const float*)d_in[14];
    const float* nb2 = (const float*)d_in[15];

    char* ws = (char*)d_ws;
    float* agg    = (float*)(ws + 0);           // 25,600,000 B
    short* eW1t   = (short*)(ws + 25600000);    //    196,608 B [256][384]
    short* eW2t   = (short*)(ws + 25796608);    //     65,536 B [128][256]
    short* nW1t   = (short*)(ws + 25862144);    //    131,072 B [256][256]
    short* nW2t   = (short*)(ws + 25993216);    //     65,536 B [128][256]
    short* nodesBF= (short*)(ws + 26058752);    // 12,800,000 B [N][128] bf16
    float* aggscr = (float*)(ws + 38858752);    // 25,600,000 B ablation scratch

    float* nodes_out = (float*)d_out;
    float* edges_out = nodes_out + (size_t)N_CNT * DD;

    hipMemsetAsync(agg, 0, (size_t)N_CNT * DD * sizeof(float), stream);

    wtrans<<<(384 * 256 + 255) / 256, 256, 0, stream>>>(eW1, eW1t, 384, 256);
    wtrans<<<(256 * 128 + 255) / 256, 256, 0, stream>>>(eW2, eW2t, 256, 128);
    wtrans<<<(256 * 256 + 255) / 256, 256, 0, stream>>>(nW1, nW1t, 256, 256);
    wtrans<<<(256 * 128 + 255) / 256, 256, 0, stream>>>(nW2, nW2t, 256, 128);
    castbf<<<(N_CNT * DD / 8 + 255) / 256, 256, 0, stream>>>(nodes, nodesBF, N_CNT * DD / 8);

    edge_kernel<<<(E_CNT + 63) / 64, 512, 0, stream>>>(
        edges, senders, receivers, nodesBF, eW1t, eW2t,
        eb1, eg, ebt, eb2, agg, edges_out);

    node_kernel<<<(N_CNT + 63) / 64, 512, 0, stream>>>(
        nodes, agg, nW1t, nW2t, nb1, ng, nbt, nb2, nodes_out);

    // ---- ablation dispatches (scratch-only, measured via rocprof) ----
    const int NTILE = (E_CNT + 63) / 64;   // 7813
    abl_stage4<<<(NTILE + 3) / 4, 512, 0, stream>>>(
        edges, senders, receivers, nodesBF, aggscr);
    abl_atomic2<<<NTILE, 512, 0, stream>>>(receivers, aggscr);
}

// Round 9
// 791.358 us; speedup vs baseline: 1.5774x; 1.5774x over previous
//
#include <hip/hip_runtime.h>

#define E_CNT 500000
#define N_CNT 50000
#define DD 128
#define HH 256
#define LN_EPS 1e-5f

typedef __attribute__((ext_vector_type(8))) short bh8;   // 8 x bf16 (MFMA A/B frag)
typedef __attribute__((ext_vector_type(4))) float fx4;   // MFMA C/D frag

__device__ __forceinline__ float b2f(short s) {
    return __uint_as_float(((unsigned)(unsigned short)s) << 16);
}
__device__ __forceinline__ short f2b(float f) {
    unsigned x = __float_as_uint(f);
    x += 0x7fffu + ((x >> 16) & 1u);   // RNE
    return (short)(x >> 16);
}
__device__ __forceinline__ fx4 mfma16(bh8 a, bh8 b, fx4 c) {
    return __builtin_amdgcn_mfma_f32_16x16x32_bf16(a, b, c, 0, 0, 0);
}
// byte-offset XOR swizzle for a [*][128] bf16 plane (256B rows)
__device__ __forceinline__ int swz128(int row, int k) {
    return ((row * 128 + k) * 2) ^ ((row & 7) << 4);
}
__device__ __forceinline__ int swz256(int row, int c) {   // [*][256] bf16 tile
    return ((row * 256 + c) * 2) ^ ((row & 7) << 4);
}
__device__ __forceinline__ bh8 pack8(const float* s) {
    float4 f0 = *(const float4*)s, f1 = *(const float4*)(s + 4);
    bh8 v;
    v[0] = f2b(f0.x); v[1] = f2b(f0.y); v[2] = f2b(f0.z); v[3] = f2b(f0.w);
    v[4] = f2b(f1.x); v[5] = f2b(f1.y); v[6] = f2b(f1.z); v[7] = f2b(f1.w);
    return v;
}

// ---------------------------------------------------------------------------
__global__ void wtrans(const float* __restrict__ src, short* __restrict__ dst,
                       int K, int N) {
    int idx = blockIdx.x * 256 + threadIdx.x;
    if (idx >= K * N) return;
    int n = idx / K, k = idx - n * K;
    dst[idx] = f2b(src[(size_t)k * N + n]);
}

__global__ void castbf(const float* __restrict__ src, short* __restrict__ dst, int n8) {
    int i = blockIdx.x * 256 + threadIdx.x;
    if (i < n8) *(bh8*)(dst + (size_t)i * 8) = pack8(src + (size_t)i * 8);
}

// ---------------------------------------------------------------------------
// Edge kernel v9: fused K=384 GEMM1 (R7 traffic) + register-staged gathers
// with IMPLICIT scheduling (R2 overlap) — no DMA, no vmcnt(0) drain, no raw
// barriers; 3 __syncthreads total. LDS 50KB + launch_bounds(512,3) -> 3 blk/CU.
//   A = [edges | nodesBF[s] | nodesBF[r]]: 3 LDS planes [64][128] bf16.
//   pre = A@W1(K=384)+eb1 -> LN(in-reg) -> relu -> H (overwrites planes 1,2)
//   -> GEMM2 -> +eb2 + residual(plane0) -> store + atomicAdd scatter.
// ---------------------------------------------------------------------------
__launch_bounds__(512, 3)
__global__ void edge_kernel(const float* __restrict__ edges,
                            const int* __restrict__ senders,
                            const int* __restrict__ receivers,
                            const short* __restrict__ nodesBF, // [N][128] bf16
                            const short* __restrict__ eW1t,    // [256][384]
                            const short* __restrict__ eW2t,    // [128][256]
                            const float* __restrict__ eb1,
                            const float* __restrict__ eg,
                            const float* __restrict__ ebt,
                            const float* __restrict__ eb2,
                            float* __restrict__ agg,
                            float* __restrict__ edges_out) {
    __shared__ short Apl[3][64 * 128];   // 48KB: edges | senders | receivers
    __shared__ float P[64][4][2];        // LN partials [row][wn][sum,sumsq]

    const int tid = threadIdx.x;
    const int l = tid & 63, wid = tid >> 6, lg = l >> 4, lo = l & 15;
    const int e0 = blockIdx.x * 64;

    // ---- stage (all loads issued up-front; compiler-scheduled overlap) ----
    // edges: 1024 chunks of 8 floats; 512 thr -> 2 each
    float4 ef[2][2];
    bh8 gs[2], gr[2];
    #pragma unroll
    for (int it = 0; it < 2; ++it) {
        int ch = tid + 512 * it;
        int row = ch >> 4, c = ch & 15;
        int e = e0 + row; if (e >= E_CNT) e = E_CNT - 1;
        const float* p = edges + (size_t)e * DD + c * 8;
        ef[it][0] = *(const float4*)p;
        ef[it][1] = *(const float4*)(p + 4);
        // node gathers: 16 consecutive threads read one 256B row (coalesced)
        gs[it] = *(const bh8*)(nodesBF + (size_t)senders[e] * DD + c * 8);
        gr[it] = *(const bh8*)(nodesBF + (size_t)receivers[e] * DD + c * 8);
    }
    #pragma unroll
    for (int it = 0; it < 2; ++it) {
        int ch = tid + 512 * it;
        int row = ch >> 4, c = ch & 15;
        bh8 v;
        v[0] = f2b(ef[it][0].x); v[1] = f2b(ef[it][0].y);
        v[2] = f2b(ef[it][0].z); v[3] = f2b(ef[it][0].w);
        v[4] = f2b(ef[it][1].x); v[5] = f2b(ef[it][1].y);
        v[6] = f2b(ef[it][1].z); v[7] = f2b(ef[it][1].w);
        *(bh8*)((char*)Apl[0] + swz128(row, c * 8)) = v;
        *(bh8*)((char*)Apl[1] + swz128(row, c * 8)) = gs[it];
        *(bh8*)((char*)Apl[2] + swz128(row, c * 8)) = gr[it];
    }
    __syncthreads();

    // hoisted per-column constants (L2-hot)
    const int wn = wid & 3, wm = wid >> 2;
    const int wn2 = wid & 1, wm2 = wid >> 1;
    float eb1c[4], egc[4], ebtc[4], eb2c[4];
    #pragma unroll
    for (int j = 0; j < 4; ++j) {
        int col = wn * 64 + 16 * j + lo;
        eb1c[j] = eb1[col]; egc[j] = eg[col]; ebtc[j] = ebt[col];
        eb2c[j] = eb2[wn2 * 64 + 16 * j + lo];
    }

    // ---- GEMM1: A[64x384] @ W1 -> acc[64x256]; wave = 32 rows x 64 cols ----
    fx4 acc[2][4] = {};
    #pragma unroll
    for (int kk = 0; kk < 12; ++kk) {
        int p = kk >> 2;
        int krow = (kk & 3) * 32 + lg * 8;
        bh8 a[2], b[4];
        #pragma unroll
        for (int i = 0; i < 2; ++i)
            a[i] = *(const bh8*)((char*)Apl[p] + swz128(wm * 32 + 16 * i + lo, krow));
        #pragma unroll
        for (int j = 0; j < 4; ++j)
            b[j] = *(const bh8*)(eW1t + (size_t)(wn * 64 + 16 * j + lo) * 384 + p * 128 + krow);
        #pragma unroll
        for (int i = 0; i < 2; ++i)
            #pragma unroll
            for (int j = 0; j < 4; ++j)
                acc[i][j] = mfma16(a[i], b[j], acc[i][j]);
    }

    // ---- LN stats (in-register, +eb1) ----
    #pragma unroll
    for (int i = 0; i < 2; ++i)
        #pragma unroll
        for (int r = 0; r < 4; ++r) {
            int row = wm * 32 + 16 * i + lg * 4 + r;
            float s = 0.f, q = 0.f;
            #pragma unroll
            for (int j = 0; j < 4; ++j) {
                float v = acc[i][j][r] + eb1c[j];
                acc[i][j][r] = v;
                s += v; q += v * v;
            }
            #pragma unroll
            for (int m = 1; m < 16; m <<= 1) {
                s += __shfl_xor(s, m);
                q += __shfl_xor(q, m);
            }
            if (lo == 0) { P[row][wn][0] = s; P[row][wn][1] = q; }
        }
    __syncthreads();   // P visible; all GEMM1 plane reads complete

    // ---- LN+relu -> H (overwrites planes 1,2: col<128 -> pl1, else pl2) ----
    #pragma unroll
    for (int i = 0; i < 2; ++i)
        #pragma unroll
        for (int r = 0; r < 4; ++r) {
            int row = wm * 32 + 16 * i + lg * 4 + r;
            float s = P[row][0][0] + P[row][1][0] + P[row][2][0] + P[row][3][0];
            float q = P[row][0][1] + P[row][1][1] + P[row][2][1] + P[row][3][1];
            float mean = s * (1.0f / 256.0f);
            float var = q * (1.0f / 256.0f) - mean * mean;
            float rstd = rsqrtf(var + LN_EPS);
            #pragma unroll
            for (int j = 0; j < 4; ++j) {
                int col = wn * 64 + 16 * j + lo;
                float v = (acc[i][j][r] - mean) * rstd * egc[j] + ebtc[j];
                v = fmaxf(v, 0.0f);
                *(short*)((char*)Apl[1 + (col >> 7)] + swz128(row, col & 127)) = f2b(v);
            }
        }
    __syncthreads();

    // ---- GEMM2: H[64x256] @ eW2 -> [64x128]; wave = 16 rows x 64 cols ----
    fx4 acc2[4] = {};
    #pragma unroll
    for (int kk = 0; kk < 8; ++kk) {
        int k0 = kk * 32 + lg * 8;
        bh8 a2 = *(const bh8*)((char*)Apl[1 + (k0 >> 7)] + swz128(wm2 * 16 + lo, k0 & 127));
        #pragma unroll
        for (int j = 0; j < 4; ++j) {
            bh8 b = *(const bh8*)(eW2t + (size_t)(wn2 * 64 + 16 * j + lo) * HH + k0);
            acc2[j] = mfma16(a2, b, acc2[j]);
        }
    }
    // ---- epilogue: +eb2, residual from plane0, store, atomic scatter ----
    int eR[4], rcv[4];
    #pragma unroll
    for (int r = 0; r < 4; ++r) {
        int e = e0 + wm2 * 16 + lg * 4 + r;
        eR[r] = e;
        rcv[r] = receivers[e < E_CNT ? e : E_CNT - 1];
    }
    #pragma unroll
    for (int j = 0; j < 4; ++j) {
        #pragma unroll
        for (int r = 0; r < 4; ++r) {
            if (eR[r] < E_CNT) {
                int row = wm2 * 16 + lg * 4 + r;
                int col = wn2 * 64 + 16 * j + lo;
                float upd = acc2[j][r] + eb2c[j];
                float res = b2f(*(const short*)((char*)Apl[0] + swz128(row, col)));
                edges_out[(size_t)eR[r] * DD + col] = upd + res;
                atomicAdd(agg + (size_t)rcv[r] * DD + col, upd);
            }
        }
    }
}

// ---------------------------------------------------------------------------
// Node kernel, BM=64, single X buffer: nx=[nodes|agg] -> GEMM1 (K=256) ->
// LN/relu -> GEMM2 + nb2 + nodes
// ---------------------------------------------------------------------------
__launch_bounds__(512, 2)
__global__ void node_kernel(const float* __restrict__ nodes,
                            const float* __restrict__ agg,
                            const short* __restrict__ nW1t,   // [256][256]
                            const short* __restrict__ nW2t,   // [128][256]
                            const float* __restrict__ nb1,
                            const float* __restrict__ ng,
                            const float* __restrict__ nbt,
                            const float* __restrict__ nb2,
                            float* __restrict__ nodes_out) {
    __shared__ char X[64 * 256 * 2];
    __shared__ float P[64][4][2];

    const int tid = threadIdx.x;
    const int l = tid & 63, wid = tid >> 6;
    const int n0 = blockIdx.x * 64;

    #pragma unroll
    for (int it = 0; it < 4; ++it) {
        int c = tid + 512 * it;
        int row = c >> 5, cc = (c & 31) * 8;
        int n = n0 + row; if (n >= N_CNT) n = N_CNT - 1;
        const float* s = (cc < DD) ? (nodes + (size_t)n * DD + cc)
                                   : (agg + (size_t)n * DD + (cc - DD));
        *(bh8*)(X + swz256(row, cc)) = pack8(s);
    }
    __syncthreads();

    const int wm = wid >> 2, wn = wid & 3;
    fx4 acc[2][4] = {};
    #pragma unroll
    for (int kk = 0; kk < 8; ++kk) {
        int krow = kk * 32 + (l >> 4) * 8;
        bh8 a[2], b[4];
        #pragma unroll
        for (int i = 0; i < 2; ++i)
            a[i] = *(const bh8*)(X + swz256(wm * 32 + 16 * i + (l & 15), krow));
        #pragma unroll
        for (int j = 0; j < 4; ++j)
            b[j] = *(const bh8*)(nW1t + (size_t)(wn * 64 + 16 * j + (l & 15)) * 256 + krow);
        #pragma unroll
        for (int i = 0; i < 2; ++i)
            #pragma unroll
            for (int j = 0; j < 4; ++j)
                acc[i][j] = mfma16(a[i], b[j], acc[i][j]);
    }
    __syncthreads();

    float nb1c[4], ngc[4], nbtc[4];
    #pragma unroll
    for (int j = 0; j < 4; ++j) {
        int col = wn * 64 + 16 * j + (l & 15);
        nb1c[j] = nb1[col]; ngc[j] = ng[col]; nbtc[j] = nbt[col];
    }
    #pragma unroll
    for (int i = 0; i < 2; ++i)
        #pragma unroll
        for (int r = 0; r < 4; ++r) {
            int row = wm * 32 + 16 * i + (l >> 4) * 4 + r;
            float s = 0.f, q = 0.f;
            #pragma unroll
            for (int j = 0; j < 4; ++j) {
                float v = acc[i][j][r] + nb1c[j];
                acc[i][j][r] = v;
                s += v; q += v * v;
            }
            #pragma unroll
            for (int m = 1; m < 16; m <<= 1) {
                s += __shfl_xor(s, m);
                q += __shfl_xor(q, m);
            }
            if ((l & 15) == 0) { P[row][wn][0] = s; P[row][wn][1] = q; }
        }
    __syncthreads();

    #pragma unroll
    for (int i = 0; i < 2; ++i)
        #pragma unroll
        for (int r = 0; r < 4; ++r) {
            int row = wm * 32 + 16 * i + (l >> 4) * 4 + r;
            float s = P[row][0][0] + P[row][1][0] + P[row][2][0] + P[row][3][0];
            float q = P[row][0][1] + P[row][1][1] + P[row][2][1] + P[row][3][1];
            float mean = s * (1.0f / 256.0f);
            float var = q * (1.0f / 256.0f) - mean * mean;
            float rstd = rsqrtf(var + LN_EPS);
            #pragma unroll
            for (int j = 0; j < 4; ++j) {
                int col = wn * 64 + 16 * j + (l & 15);
                float v = (acc[i][j][r] - mean) * rstd * ngc[j] + nbtc[j];
                v = fmaxf(v, 0.0f);
                *(short*)(X + swz256(row, col)) = f2b(v);
            }
        }
    __syncthreads();

    const int wm2 = wid >> 1, wn2 = wid & 1;
    fx4 acc2[4] = {};
    #pragma unroll
    for (int kk = 0; kk < 8; ++kk) {
        int krow = kk * 32 + (l >> 4) * 8;
        bh8 a = *(const bh8*)(X + swz256(wm2 * 16 + (l & 15), krow));
        #pragma unroll
        for (int j = 0; j < 4; ++j) {
            bh8 b = *(const bh8*)(nW2t + (size_t)(wn2 * 64 + 16 * j + (l & 15)) * 256 + krow);
            acc2[j] = mfma16(a, b, acc2[j]);
        }
    }
    float nb2c[4];
    #pragma unroll
    for (int j = 0; j < 4; ++j) nb2c[j] = nb2[wn2 * 64 + 16 * j + (l & 15)];
    #pragma unroll
    for (int r = 0; r < 4; ++r) {
        int row = wm2 * 16 + (l >> 4) * 4 + r;
        int n = n0 + row;
        if (n < N_CNT) {
            #pragma unroll
            for (int j = 0; j < 4; ++j) {
                int col = wn2 * 64 + 16 * j + (l & 15);
                nodes_out[(size_t)n * DD + col] =
                    acc2[j][r] + nb2c[j] + nodes[(size_t)n * DD + col];
            }
        }
    }
}

// ---------------------------------------------------------------------------
extern "C" void kernel_launch(void* const* d_in, const int* in_sizes, int n_in,
                              void* d_out, int out_size, void* d_ws, size_t ws_size,
                              hipStream_t stream) {
    const float* nodes = (const float*)d_in[0];
    const float* edges = (const float*)d_in[1];
    const int* senders = (const int*)d_in[2];
    const int* receivers = (const int*)d_in[3];
    const float* eW1 = (const float*)d_in[4];
    const float* eb1 = (const float*)d_in[5];
    const float* eg  = (const float*)d_in[6];
    const float* ebt = (const float*)d_in[7];
    const float* eW2 = (const float*)d_in[8];
    const float* eb2 = (const float*)d_in[9];
    const float* nW1 = (const float*)d_in[10];
    const float* nb1 = (const float*)d_in[11];
    const float* ng  = (const float*)d_in[12];
    const float* nbt = (const float*)d_in[13];
    const float* nW2 = (const float*)d_in[14];
    const float* nb2 = (const float*)d_in[15];

    char* ws = (char*)d_ws;
    float* agg    = (float*)(ws + 0);           // 25,600,000 B
    short* eW1t   = (short*)(ws + 25600000);    //    196,608 B [256][384]
    short* eW2t   = (short*)(ws + 25796608);    //     65,536 B [128][256]
    short* nW1t   = (short*)(ws + 25862144);    //    131,072 B [256][256]
    short* nW2t   = (short*)(ws + 25993216);    //     65,536 B [128][256]
    short* nodesBF= (short*)(ws + 26058752);    // 12,800,000 B [N][128] bf16

    float* nodes_out = (float*)d_out;
    float* edges_out = nodes_out + (size_t)N_CNT * DD;

    hipMemsetAsync(agg, 0, (size_t)N_CNT * DD * sizeof(float), stream);

    wtrans<<<(384 * 256 + 255) / 256, 256, 0, stream>>>(eW1, eW1t, 384, 256);
    wtrans<<<(256 * 128 + 255) / 256, 256, 0, stream>>>(eW2, eW2t, 256, 128);
    wtrans<<<(256 * 256 + 255) / 256, 256, 0, stream>>>(nW1, nW1t, 256, 256);
    wtrans<<<(256 * 128 + 255) / 256, 256, 0, stream>>>(nW2, nW2t, 256, 128);
    castbf<<<(N_CNT * DD / 8 + 255) / 256, 256, 0, stream>>>(nodes, nodesBF, N_CNT * DD / 8);

    edge_kernel<<<(E_CNT + 63) / 64, 512, 0, stream>>>(
        edges, senders, receivers, nodesBF, eW1t, eW2t,
        eb1, eg, ebt, eb2, agg, edges_out);

    node_kernel<<<(N_CNT + 63) / 64, 512, 0, stream>>>(
        nodes, agg, nW1t, nW2t, nb1, ng, nbt, nb2, nodes_out);
}

// Round 10
// 612.100 us; speedup vs baseline: 2.0394x; 1.2929x over previous
//
#include <hip/hip_runtime.h>

#define E_CNT 500000
#define N_CNT 50000
#define DD 128
#define HH 256
#define LN_EPS 1e-5f

typedef __attribute__((ext_vector_type(8))) short bh8;   // 8 x bf16 (MFMA A/B frag)
typedef __attribute__((ext_vector_type(4))) float fx4;   // MFMA C/D frag

__device__ __forceinline__ float b2f(short s) {
    return __uint_as_float(((unsigned)(unsigned short)s) << 16);
}
__device__ __forceinline__ short f2b(float f) {
    unsigned x = __float_as_uint(f);
    x += 0x7fffu + ((x >> 16) & 1u);   // RNE
    return (short)(x >> 16);
}
__device__ __forceinline__ fx4 mfma16(bh8 a, bh8 b, fx4 c) {
    return __builtin_amdgcn_mfma_f32_16x16x32_bf16(a, b, c, 0, 0, 0);
}
__device__ __forceinline__ int swz128(int row, int k) {   // [*][128] bf16 tile
    return ((row * 128 + k) * 2) ^ ((row & 7) << 4);
}
__device__ __forceinline__ int swz256(int row, int c) {   // [*][256] bf16 tile
    return ((row * 256 + c) * 2) ^ ((row & 7) << 4);
}
__device__ __forceinline__ bh8 pack8(const float* s) {
    float4 f0 = *(const float4*)s, f1 = *(const float4*)(s + 4);
    bh8 v;
    v[0] = f2b(f0.x); v[1] = f2b(f0.y); v[2] = f2b(f0.z); v[3] = f2b(f0.w);
    v[4] = f2b(f1.x); v[5] = f2b(f1.y); v[6] = f2b(f1.z); v[7] = f2b(f1.w);
    return v;
}

// ---------------------------------------------------------------------------
// Weight transpose-convert: dst[n][k] = bf16(src[k][n]); src is [K][N] f32.
// ---------------------------------------------------------------------------
__global__ void wtrans(const float* __restrict__ src, short* __restrict__ dst,
                       int K, int N) {
    int idx = blockIdx.x * 256 + threadIdx.x;
    if (idx >= K * N) return;
    int n = idx / K, k = idx - n * K;
    dst[idx] = f2b(src[(size_t)k * N + n]);
}

// packed GEMM1 B for edge kernel: eW1a[n][k] = bf16(eW1[k][n]), k<128
__global__ void wtransA(const float* __restrict__ src, short* __restrict__ dst) {
    int idx = blockIdx.x * 256 + threadIdx.x;
    if (idx >= 256 * 128) return;
    int n = idx >> 7, k = idx & 127;
    dst[idx] = f2b(src[(size_t)k * 256 + n]);
}

// ---------------------------------------------------------------------------
// Table precompute (R2-proven): tabS[n][h] = bf16(nodes[n]@eW1[128:256]),
//                               tabR[n][h] = bf16(nodes[n]@eW1[256:384]).
// ---------------------------------------------------------------------------
__launch_bounds__(512, 2)
__global__ void table_kernel(const float* __restrict__ nodes,
                             const short* __restrict__ eW1t,   // [256][384]
                             short* __restrict__ tabS, short* __restrict__ tabR) {
    __shared__ char Abuf[128 * 128 * 2];
    const int tid = threadIdx.x;
    const int l = tid & 63, wid = tid >> 6;
    const int wm = wid >> 2, wn = wid & 3;
    const int n0 = blockIdx.x * 128;

    for (int it = 0; it < 4; ++it) {
        int c = tid + 512 * it;
        int row = c >> 4, cc = (c & 15) * 8;
        int n = n0 + row; if (n >= N_CNT) n = N_CNT - 1;
        *(bh8*)(Abuf + swz128(row, cc)) = pack8(nodes + (size_t)n * DD + cc);
    }
    __syncthreads();

    fx4 accS[4][4] = {}; fx4 accR[4][4] = {};
    #pragma unroll
    for (int kk = 0; kk < 4; ++kk) {
        int krow = kk * 32 + (l >> 4) * 8;
        bh8 a[4], bs[4], br[4];
        #pragma unroll
        for (int i = 0; i < 4; ++i)
            a[i] = *(const bh8*)(Abuf + swz128(wm * 64 + 16 * i + (l & 15), krow));
        #pragma unroll
        for (int j = 0; j < 4; ++j) {
            const short* bp = eW1t + (size_t)(wn * 64 + 16 * j + (l & 15)) * 384 + krow;
            bs[j] = *(const bh8*)(bp + 128);
            br[j] = *(const bh8*)(bp + 256);
        }
        #pragma unroll
        for (int i = 0; i < 4; ++i)
            #pragma unroll
            for (int j = 0; j < 4; ++j) {
                accS[i][j] = mfma16(a[i], bs[j], accS[i][j]);
                accR[i][j] = mfma16(a[i], br[j], accR[i][j]);
            }
    }
    #pragma unroll
    for (int i = 0; i < 4; ++i)
        #pragma unroll
        for (int r = 0; r < 4; ++r) {
            int row = wm * 64 + 16 * i + (l >> 4) * 4 + r;
            int n = n0 + row;
            if (n < N_CNT) {
                #pragma unroll
                for (int j = 0; j < 4; ++j) {
                    int col = wn * 64 + 16 * j + (l & 15);
                    tabS[(size_t)n * HH + col] = f2b(accS[i][j][r]);
                    tabR[(size_t)n * HH + col] = f2b(accR[i][j][r]);
                }
            }
        }
}

// ---------------------------------------------------------------------------
// Edge kernel v10: R2 structure, small blocks for block-level TLP.
// 256 threads (4 waves), BM=32 edges, LDS ~25KB -> 4 blocks/CU (reg-capped).
//   pre = edges@W1a (K=128 MFMA) + tabS[s]+tabR[r] + eb1
//   h   = relu(LN(pre)) -> Sbuf;  upd = h@eW2 + eb2
//   edges_out = upd + residual(Abuf);  atomicAdd(agg[recv], upd)
// ---------------------------------------------------------------------------
__launch_bounds__(256, 4)
__global__ void edge_kernel(const float* __restrict__ edges,
                            const int* __restrict__ senders,
                            const int* __restrict__ receivers,
                            const short* __restrict__ tabS,
                            const short* __restrict__ tabR,
                            const short* __restrict__ eW1a,   // [256][128]
                            const short* __restrict__ eW2t,   // [128][256]
                            const float* __restrict__ eb1,
                            const float* __restrict__ eg,
                            const float* __restrict__ ebt,
                            const float* __restrict__ eb2,
                            float* __restrict__ agg,
                            float* __restrict__ edges_out) {
    __shared__ short Abuf[32 * 128];     //  8KB edges tile (bf16, swizzled)
    __shared__ short Sbuf[32 * 256];     // 16KB table-sum, later H
    __shared__ float P[32][4][2];        //  1KB LN partials
    __shared__ int irecv[32];

    const int tid = threadIdx.x;
    const int l = tid & 63, wid = tid >> 6, lg = l >> 4, lo = l & 15;
    const int e0 = blockIdx.x * 32;

    if (tid < 32) {
        int e = e0 + tid; if (e >= E_CNT) e = E_CNT - 1;
        irecv[tid] = receivers[e];
    }

    // ---- stage A: 32 rows x 128 cols; 512 chunks / 256 thr = 2 each ----
    #pragma unroll
    for (int it = 0; it < 2; ++it) {
        int ch = tid + 256 * it;
        int row = ch >> 4, c = (ch & 15) * 8;
        int e = e0 + row; if (e >= E_CNT) e = E_CNT - 1;
        *(bh8*)((char*)Abuf + swz128(row, c)) = pack8(edges + (size_t)e * DD + c);
    }
    // ---- issue table gathers into regs (consumed after GEMM1) ----
    bh8 ts[4], tr[4];
    #pragma unroll
    for (int it = 0; it < 4; ++it) {
        int ch = tid + 256 * it;                 // 1024 chunks of 8 bf16
        int row = ch >> 5, cc = (ch & 31) * 8;
        int e = e0 + row; if (e >= E_CNT) e = E_CNT - 1;
        ts[it] = *(const bh8*)(tabS + (size_t)senders[e] * HH + cc);
        tr[it] = *(const bh8*)(tabR + (size_t)receivers[e] * HH + cc);
    }
    __syncthreads();

    // ---- GEMM1: A[32x128] @ W1a -> acc[32x256]; wave = 32 rows x 64 cols ----
    const int wn = wid;                          // 4 waves = 4 col groups
    fx4 acc[2][4] = {};
    #pragma unroll
    for (int kk = 0; kk < 4; ++kk) {
        int krow = kk * 32 + lg * 8;
        bh8 a[2], b[4];
        #pragma unroll
        for (int i = 0; i < 2; ++i)
            a[i] = *(const bh8*)((char*)Abuf + swz128(16 * i + lo, krow));
        #pragma unroll
        for (int j = 0; j < 4; ++j)
            b[j] = *(const bh8*)(eW1a + (size_t)(wn * 64 + 16 * j + lo) * 128 + krow);
        #pragma unroll
        for (int i = 0; i < 2; ++i)
            #pragma unroll
            for (int j = 0; j < 4; ++j)
                acc[i][j] = mfma16(a[i], b[j], acc[i][j]);
    }

    // ---- combine gathered tables -> Sbuf ----
    #pragma unroll
    for (int it = 0; it < 4; ++it) {
        int ch = tid + 256 * it;
        int row = ch >> 5, cc = (ch & 31) * 8;
        bh8 v;
        #pragma unroll
        for (int q = 0; q < 8; ++q) v[q] = f2b(b2f(ts[it][q]) + b2f(tr[it][q]));
        *(bh8*)((char*)Sbuf + swz256(row, cc)) = v;
    }
    __syncthreads();

    // ---- epilogue 1: + table-sum + eb1, LN partials ----
    float eb1c[4], egc[4], ebtc[4];
    #pragma unroll
    for (int j = 0; j < 4; ++j) {
        int col = wn * 64 + 16 * j + lo;
        eb1c[j] = eb1[col]; egc[j] = eg[col]; ebtc[j] = ebt[col];
    }
    #pragma unroll
    for (int i = 0; i < 2; ++i)
        #pragma unroll
        for (int r = 0; r < 4; ++r) {
            int row = 16 * i + lg * 4 + r;
            float s = 0.f, q = 0.f;
            #pragma unroll
            for (int j = 0; j < 4; ++j) {
                int col = wn * 64 + 16 * j + lo;
                float v = acc[i][j][r] + eb1c[j] +
                          b2f(*(const short*)((char*)Sbuf + swz256(row, col)));
                acc[i][j][r] = v;
                s += v; q += v * v;
            }
            #pragma unroll
            for (int m = 1; m < 16; m <<= 1) {
                s += __shfl_xor(s, m);
                q += __shfl_xor(q, m);
            }
            if (lo == 0) { P[row][wn][0] = s; P[row][wn][1] = q; }
        }
    __syncthreads();   // Sbuf reads done; partials visible

    // ---- epilogue 2: LN + relu -> H into Sbuf (same-thread cells) ----
    #pragma unroll
    for (int i = 0; i < 2; ++i)
        #pragma unroll
        for (int r = 0; r < 4; ++r) {
            int row = 16 * i + lg * 4 + r;
            float s = P[row][0][0] + P[row][1][0] + P[row][2][0] + P[row][3][0];
            float q = P[row][0][1] + P[row][1][1] + P[row][2][1] + P[row][3][1];
            float mean = s * (1.0f / 256.0f);
            float var = q * (1.0f / 256.0f) - mean * mean;
            float rstd = rsqrtf(var + LN_EPS);
            #pragma unroll
            for (int j = 0; j < 4; ++j) {
                int col = wn * 64 + 16 * j + lo;
                float v = (acc[i][j][r] - mean) * rstd * egc[j] + ebtc[j];
                v = fmaxf(v, 0.0f);
                *(short*)((char*)Sbuf + swz256(row, col)) = f2b(v);
            }
        }
    __syncthreads();

    // ---- GEMM2: H[32x256] @ eW2 -> [32x128]; wave = 16 rows x 64 cols ----
    const int wm2 = wid >> 1, wn2 = wid & 1;
    fx4 acc2[4] = {};
    #pragma unroll
    for (int kk = 0; kk < 8; ++kk) {
        int krow = kk * 32 + lg * 8;
        bh8 a = *(const bh8*)((char*)Sbuf + swz256(wm2 * 16 + lo, krow));
        #pragma unroll
        for (int j = 0; j < 4; ++j) {
            bh8 b = *(const bh8*)(eW2t + (size_t)(wn2 * 64 + 16 * j + lo) * HH + krow);
            acc2[j] = mfma16(a, b, acc2[j]);
        }
    }
    float eb2c[4];
    #pragma unroll
    for (int j = 0; j < 4; ++j) eb2c[j] = eb2[wn2 * 64 + 16 * j + lo];
    #pragma unroll
    for (int r = 0; r < 4; ++r) {
        int row = wm2 * 16 + lg * 4 + r;
        int e = e0 + row;
        if (e < E_CNT) {
            int rcv = irecv[row];
            #pragma unroll
            for (int j = 0; j < 4; ++j) {
                int col = wn2 * 64 + 16 * j + lo;
                float upd = acc2[j][r] + eb2c[j];
                float res = b2f(*(const short*)((char*)Abuf + swz128(row, col)));
                edges_out[(size_t)e * DD + col] = upd + res;
                atomicAdd(agg + (size_t)rcv * DD + col, upd);
            }
        }
    }
}

// ---------------------------------------------------------------------------
// Node kernel (unchanged): nx=[nodes|agg] -> GEMM1 (K=256) -> LN/relu ->
// GEMM2 + nb2 + nodes
// ---------------------------------------------------------------------------
__launch_bounds__(512, 2)
__global__ void node_kernel(const float* __restrict__ nodes,
                            const float* __restrict__ agg,
                            const short* __restrict__ nW1t,   // [256][256]
                            const short* __restrict__ nW2t,   // [128][256]
                            const float* __restrict__ nb1,
                            const float* __restrict__ ng,
                            const float* __restrict__ nbt,
                            const float* __restrict__ nb2,
                            float* __restrict__ nodes_out) {
    __shared__ char X[64 * 256 * 2];
    __shared__ float P[64][4][2];

    const int tid = threadIdx.x;
    const int l = tid & 63, wid = tid >> 6;
    const int n0 = blockIdx.x * 64;

    #pragma unroll
    for (int it = 0; it < 4; ++it) {
        int c = tid + 512 * it;
        int row = c >> 5, cc = (c & 31) * 8;
        int n = n0 + row; if (n >= N_CNT) n = N_CNT - 1;
        const float* s = (cc < DD) ? (nodes + (size_t)n * DD + cc)
                                   : (agg + (size_t)n * DD + (cc - DD));
        *(bh8*)(X + swz256(row, cc)) = pack8(s);
    }
    __syncthreads();

    const int wm = wid >> 2, wn = wid & 3;
    fx4 acc[2][4] = {};
    #pragma unroll
    for (int kk = 0; kk < 8; ++kk) {
        int krow = kk * 32 + (l >> 4) * 8;
        bh8 a[2], b[4];
        #pragma unroll
        for (int i = 0; i < 2; ++i)
            a[i] = *(const bh8*)(X + swz256(wm * 32 + 16 * i + (l & 15), krow));
        #pragma unroll
        for (int j = 0; j < 4; ++j)
            b[j] = *(const bh8*)(nW1t + (size_t)(wn * 64 + 16 * j + (l & 15)) * 256 + krow);
        #pragma unroll
        for (int i = 0; i < 2; ++i)
            #pragma unroll
            for (int j = 0; j < 4; ++j)
                acc[i][j] = mfma16(a[i], b[j], acc[i][j]);
    }
    __syncthreads();

    float nb1c[4], ngc[4], nbtc[4];
    #pragma unroll
    for (int j = 0; j < 4; ++j) {
        int col = wn * 64 + 16 * j + (l & 15);
        nb1c[j] = nb1[col]; ngc[j] = ng[col]; nbtc[j] = nbt[col];
    }
    #pragma unroll
    for (int i = 0; i < 2; ++i)
        #pragma unroll
        for (int r = 0; r < 4; ++r) {
            int row = wm * 32 + 16 * i + (l >> 4) * 4 + r;
            float s = 0.f, q = 0.f;
            #pragma unroll
            for (int j = 0; j < 4; ++j) {
                float v = acc[i][j][r] + nb1c[j];
                acc[i][j][r] = v;
                s += v; q += v * v;
            }
            #pragma unroll
            for (int m = 1; m < 16; m <<= 1) {
                s += __shfl_xor(s, m);
                q += __shfl_xor(q, m);
            }
            if ((l & 15) == 0) { P[row][wn][0] = s; P[row][wn][1] = q; }
        }
    __syncthreads();

    #pragma unroll
    for (int i = 0; i < 2; ++i)
        #pragma unroll
        for (int r = 0; r < 4; ++r) {
            int row = wm * 32 + 16 * i + (l >> 4) * 4 + r;
            float s = P[row][0][0] + P[row][1][0] + P[row][2][0] + P[row][3][0];
            float q = P[row][0][1] + P[row][1][1] + P[row][2][1] + P[row][3][1];
            float mean = s * (1.0f / 256.0f);
            float var = q * (1.0f / 256.0f) - mean * mean;
            float rstd = rsqrtf(var + LN_EPS);
            #pragma unroll
            for (int j = 0; j < 4; ++j) {
                int col = wn * 64 + 16 * j + (l & 15);
                float v = (acc[i][j][r] - mean) * rstd * ngc[j] + nbtc[j];
                v = fmaxf(v, 0.0f);
                *(short*)(X + swz256(row, col)) = f2b(v);
            }
        }
    __syncthreads();

    const int wm2 = wid >> 1, wn2 = wid & 1;
    fx4 acc2[4] = {};
    #pragma unroll
    for (int kk = 0; kk < 8; ++kk) {
        int krow = kk * 32 + (l >> 4) * 8;
        bh8 a = *(const bh8*)(X + swz256(wm2 * 16 + (l & 15), krow));
        #pragma unroll
        for (int j = 0; j < 4; ++j) {
            bh8 b = *(const bh8*)(nW2t + (size_t)(wn2 * 64 + 16 * j + (l & 15)) * 256 + krow);
            acc2[j] = mfma16(a, b, acc2[j]);
        }
    }
    float nb2c[4];
    #pragma unroll
    for (int j = 0; j < 4; ++j) nb2c[j] = nb2[wn2 * 64 + 16 * j + (l & 15)];
    #pragma unroll
    for (int r = 0; r < 4; ++r) {
        int row = wm2 * 16 + (l >> 4) * 4 + r;
        int n = n0 + row;
        if (n < N_CNT) {
            #pragma unroll
            for (int j = 0; j < 4; ++j) {
                int col = wn2 * 64 + 16 * j + (l & 15);
                nodes_out[(size_t)n * DD + col] =
                    acc2[j][r] + nb2c[j] + nodes[(size_t)n * DD + col];
            }
        }
    }
}

// ---------------------------------------------------------------------------
extern "C" void kernel_launch(void* const* d_in, const int* in_sizes, int n_in,
                              void* d_out, int out_size, void* d_ws, size_t ws_size,
                              hipStream_t stream) {
    const float* nodes = (const float*)d_in[0];
    const float* edges = (const float*)d_in[1];
    const int* senders = (const int*)d_in[2];
    const int* receivers = (const int*)d_in[3];
    const float* eW1 = (const float*)d_in[4];
    const float* eb1 = (const float*)d_in[5];
    const float* eg  = (const float*)d_in[6];
    const float* ebt = (const float*)d_in[7];
    const float* eW2 = (const float*)d_in[8];
    const float* eb2 = (const float*)d_in[9];
    const float* nW1 = (const float*)d_in[10];
    const float* nb1 = (const float*)d_in[11];
    const float* ng  = (const float*)d_in[12];
    const float* nbt = (const float*)d_in[13];
    const float* nW2 = (const float*)d_in[14];
    const float* nb2 = (const float*)d_in[15];

    char* ws = (char*)d_ws;
    float* agg  = (float*)(ws + 0);             // 25,600,000 B
    short* eW1t = (short*)(ws + 25600000);      //    196,608 B [256][384]
    short* eW2t = (short*)(ws + 25796608);      //     65,536 B [128][256]
    short* nW1t = (short*)(ws + 25862144);      //    131,072 B [256][256]
    short* nW2t = (short*)(ws + 25993216);      //     65,536 B [128][256]
    short* eW1a = (short*)(ws + 26058752);      //     65,536 B [256][128]
    short* tabS = (short*)(ws + 26124288);      // 25,600,000 B [N][256]
    short* tabR = (short*)(ws + 51724288);      // 25,600,000 B [N][256]

    float* nodes_out = (float*)d_out;
    float* edges_out = nodes_out + (size_t)N_CNT * DD;

    hipMemsetAsync(agg, 0, (size_t)N_CNT * DD * sizeof(float), stream);

    wtrans<<<(384 * 256 + 255) / 256, 256, 0, stream>>>(eW1, eW1t, 384, 256);
    wtrans<<<(256 * 128 + 255) / 256, 256, 0, stream>>>(eW2, eW2t, 256, 128);
    wtrans<<<(256 * 256 + 255) / 256, 256, 0, stream>>>(nW1, nW1t, 256, 256);
    wtrans<<<(256 * 128 + 255) / 256, 256, 0, stream>>>(nW2, nW2t, 256, 128);
    wtransA<<<(256 * 128 + 255) / 256, 256, 0, stream>>>(eW1, eW1a);

    table_kernel<<<(N_CNT + 127) / 128, 512, 0, stream>>>(nodes, eW1t, tabS, tabR);

    edge_kernel<<<(E_CNT + 31) / 32, 256, 0, stream>>>(
        edges, senders, receivers, tabS, tabR, eW1a, eW2t,
        eb1, eg, ebt, eb2, agg, edges_out);

    node_kernel<<<(N_CNT + 63) / 64, 512, 0, stream>>>(
        nodes, agg, nW1t, nW2t, nb1, ng, nbt, nb2, nodes_out);
}